// Round 10
// baseline (236.478 us; speedup 1.0000x reference)
//
#include <hip/hip_runtime.h>
#include <hip/hip_bf16.h>

#define NN 100000
#define NE 1600000

#define NBUCK  511       // buckets of BRANGE destination nodes
#define BRANGE 196       // fits 8-bit local id
#define CAPB   3584      // bucket capacity: mean 3136, sigma 56 -> 8-sigma margin
#define CHUNK  8192      // edges per bin block (196 blocks; 4096 regressed in R9)
#define NCH    196       // ceil(NE/CHUNK)

typedef __attribute__((ext_vector_type(8))) short bf16x8;
typedef __attribute__((ext_vector_type(4))) float f32x4;

__device__ inline float2 bf16x2_unpack(unsigned v) {
    float2 r;
    r.x = __uint_as_float(v << 16);
    r.y = __uint_as_float(v & 0xffff0000u);
    return r;
}
__device__ inline unsigned bf16x2_pack(float a, float b) {
    __hip_bfloat162 h2(__float2bfloat16(a), __float2bfloat16(b));
    unsigned u;
    __builtin_memcpy(&u, &h2, 4);
    return u;
}

// ---- phase 1: block-local counting sort by bucket + bulk-reserved dense runs ----
__global__ __launch_bounds__(256) void bin_kernel(const int* __restrict__ rows,
                                                  const int* __restrict__ cols,
                                                  int* __restrict__ cur,
                                                  unsigned* __restrict__ eb) {
    __shared__ int hist[512];
    __shared__ int excl[512];
    __shared__ int lcur[512];
    __shared__ int gbase[512];
    __shared__ int s2[256];
    __shared__ unsigned staged[CHUNK];
    __shared__ unsigned short bktarr[CHUNK];
    int t = threadIdx.x;
    int base = blockIdx.x * CHUNK;
    int cnt = min(CHUNK, NE - base);

    hist[t] = 0; hist[t + 256] = 0;
    __syncthreads();
    #pragma unroll
    for (int k = 0; k < CHUNK / 256; k++) {
        int i = k * 256 + t;
        if (i < cnt) {
            int c = cols[base + i];
            atomicAdd(&hist[(unsigned)c / BRANGE], 1);
        }
    }
    __syncthreads();
    // exclusive scan of 512 entries via pair trick (256-thread Hillis-Steele)
    int a0 = hist[2 * t], a1 = hist[2 * t + 1];
    s2[t] = a0 + a1;
    __syncthreads();
    #pragma unroll
    for (int off = 1; off < 256; off <<= 1) {
        int v = (t >= off) ? s2[t - off] : 0;
        __syncthreads();
        s2[t] += v;
        __syncthreads();
    }
    int pe = (t > 0) ? s2[t - 1] : 0;
    excl[2 * t] = pe;      excl[2 * t + 1] = pe + a0;
    lcur[2 * t] = pe;      lcur[2 * t + 1] = pe + a0;
    gbase[2 * t]     = a0 ? atomicAdd(cur + 2 * t, a0) : 0;
    gbase[2 * t + 1] = a1 ? atomicAdd(cur + 2 * t + 1, a1) : 0;
    __syncthreads();
    // sort records into LDS
    #pragma unroll
    for (int k = 0; k < CHUNK / 256; k++) {
        int i = k * 256 + t;
        if (i < cnt) {
            int c = cols[base + i];
            int r = rows[base + i];
            int bkt = (unsigned)c / BRANGE;
            int lp = atomicAdd(&lcur[bkt], 1);
            staged[lp] = ((unsigned)(c - bkt * BRANGE) << 24) | (unsigned)r;
            bktarr[lp] = (unsigned short)bkt;
        }
    }
    __syncthreads();
    // flat coalesced copy-out: consecutive i in a run -> consecutive gpos
    #pragma unroll
    for (int k = 0; k < CHUNK / 256; k++) {
        int i = k * 256 + t;
        if (i < cnt) {
            int bkt = bktarr[i];
            int pos = gbase[bkt] + (i - excl[bkt]);
            if (pos < CAPB) eb[(size_t)bkt * CAPB + pos] = staged[i];
        }
    }
}

// ---- phase 2: sort bucket records by dst node; emit (start,deg); fused xscale ----
__global__ __launch_bounds__(256) void nodesort_kernel(const int* __restrict__ cur,
                                                       const unsigned* __restrict__ eb,
                                                       const float* __restrict__ x,
                                                       int* __restrict__ srcs2,
                                                       int2* __restrict__ nsd,
                                                       unsigned* __restrict__ xs) {
    __shared__ int hist[256];
    __shared__ int sx[256];
    __shared__ int lcur[BRANGE];
    __shared__ float sdinv[BRANGE];
    int b = blockIdx.x, t = threadIdx.x;
    hist[t] = 0;
    __syncthreads();
    int cnt = min(cur[b], CAPB);
    const unsigned* seg = eb + (size_t)b * CAPB;
    for (int e = t; e < cnt; e += 256) atomicAdd(&hist[seg[e] >> 24], 1);
    __syncthreads();
    int h = hist[t];
    sx[t] = h;
    __syncthreads();
    #pragma unroll
    for (int off = 1; off < 256; off <<= 1) {
        int v = (t >= off) ? sx[t - off] : 0;
        __syncthreads();
        sx[t] += v;
        __syncthreads();
    }
    int ex = (t > 0) ? sx[t - 1] : 0;
    if (t < BRANGE) {
        lcur[t] = ex;
        sdinv[t] = rsqrtf((float)(h + 1));
        int n = b * BRANGE + t;
        if (n < NN) nsd[n] = make_int2(ex, h);
    }
    __syncthreads();
    for (int e = t; e < cnt; e += 256) {
        unsigned rec = seg[e];
        int p = atomicAdd(&lcur[rec >> 24], 1);
        srcs2[(size_t)b * CAPB + p] = rec & 0xFFFFFFu;
    }
    // fused xscale: xs = bf16(x * dinv) for this block's node range (dense)
    int lo = b * BRANGE;
    for (int i = t; i < BRANGE * 32; i += 256) {
        int tl = i >> 5, w = i & 31;
        int n = lo + tl;
        if (n < NN) {
            float2 v = *(const float2*)(x + (size_t)n * 64 + 2 * w);
            float dv = sdinv[tl];
            xs[(size_t)n * 32 + w] = bf16x2_pack(v.x * dv, v.y * dv);
        }
    }
}

// ---- pack Wcat[64 x 192] (3 experts side by side) into B-fragment order, bf16 ----
__global__ void wpack_kernel(const float* __restrict__ W, __hip_bfloat16* __restrict__ Bp) {
    int idx = blockIdx.x * 256 + threadIdx.x;         // 12288 total
    if (idx >= 12288) return;
    int j    = idx & 7;
    int lane = (idx >> 3) & 63;
    int rest = idx >> 9;                              // half*12 + t
    int t    = rest % 12;
    int kh   = rest / 12;
    int k    = kh * 32 + (lane >> 4) * 8 + j;
    int col  = t * 16 + (lane & 15);
    int i    = col >> 6;
    int d    = col & 63;
    Bp[idx] = __float2bfloat16(W[(i * 64 + k) * 64 + d]);
}

// ---- phase 3: FUSED gather + MFMA + gated epilogue ----
// Block = 64 nodes = 4 waves x 16 nodes. Phase A: wave gathers its 16 nodes
// (cascade-unrolled, 8 rows in flight per half-wave) into a wave-private LDS
// tile (pitch 72 bf16 = 144B -> ds_read_b128 is 2-way aliased = free).
// Phase B: wave MFMAs its own 16x192 tile from LDS, fused bias+relu+gate mix.
// Kills the hbu global round-trip and the separate mfma launch.
__global__ __launch_bounds__(256) void fused_kernel(const int* __restrict__ srcs2,
                                                    const int2* __restrict__ nsd,
                                                    const unsigned* __restrict__ xs,
                                                    const short* __restrict__ Bp,
                                                    const float* __restrict__ b,
                                                    const float* __restrict__ gf,
                                                    const float* __restrict__ Wg,
                                                    float* __restrict__ out) {
    __shared__ short hl[64 * 72];
    unsigned* hlu = (unsigned*)hl;
    int w = threadIdx.x >> 6;
    int lane = threadIdx.x & 63;
    int sub = lane >> 5;
    int dp = lane & 31;
    int nbase = blockIdx.x * 64 + w * 16;

    // ---- phase A: gather 16 nodes sequentially ----
    for (int i = 0; i < 16; i++) {
        int n = nbase + i;
        float2 acc = make_float2(0.f, 0.f);
        if (n < NN) {
            int2 sd = nsd[n];
            int deg = sd.y;
            const int* seg = srcs2 + (size_t)((unsigned)n / BRANGE) * CAPB + sd.x;
            int e = sub;
            for (; e + 14 < deg; e += 16) {           // 8 rows in flight per half
                int r0 = seg[e];      int r1 = seg[e + 2];
                int r2 = seg[e + 4];  int r3 = seg[e + 6];
                int r4 = seg[e + 8];  int r5 = seg[e + 10];
                int r6 = seg[e + 12]; int r7 = seg[e + 14];
                float2 v0 = bf16x2_unpack(xs[(size_t)r0 * 32 + dp]);
                float2 v1 = bf16x2_unpack(xs[(size_t)r1 * 32 + dp]);
                float2 v2 = bf16x2_unpack(xs[(size_t)r2 * 32 + dp]);
                float2 v3 = bf16x2_unpack(xs[(size_t)r3 * 32 + dp]);
                float2 v4 = bf16x2_unpack(xs[(size_t)r4 * 32 + dp]);
                float2 v5 = bf16x2_unpack(xs[(size_t)r5 * 32 + dp]);
                float2 v6 = bf16x2_unpack(xs[(size_t)r6 * 32 + dp]);
                float2 v7 = bf16x2_unpack(xs[(size_t)r7 * 32 + dp]);
                acc.x += ((v0.x + v1.x) + (v2.x + v3.x)) + ((v4.x + v5.x) + (v6.x + v7.x));
                acc.y += ((v0.y + v1.y) + (v2.y + v3.y)) + ((v4.y + v5.y) + (v6.y + v7.y));
            }
            for (; e + 6 < deg; e += 8) {             // 4 rows in flight
                int r0 = seg[e];     int r1 = seg[e + 2];
                int r2 = seg[e + 4]; int r3 = seg[e + 6];
                float2 v0 = bf16x2_unpack(xs[(size_t)r0 * 32 + dp]);
                float2 v1 = bf16x2_unpack(xs[(size_t)r1 * 32 + dp]);
                float2 v2 = bf16x2_unpack(xs[(size_t)r2 * 32 + dp]);
                float2 v3 = bf16x2_unpack(xs[(size_t)r3 * 32 + dp]);
                acc.x += (v0.x + v1.x) + (v2.x + v3.x);
                acc.y += (v0.y + v1.y) + (v2.y + v3.y);
            }
            for (; e + 2 < deg; e += 4) {             // 2 rows in flight
                int r0 = seg[e]; int r1 = seg[e + 2];
                float2 v0 = bf16x2_unpack(xs[(size_t)r0 * 32 + dp]);
                float2 v1 = bf16x2_unpack(xs[(size_t)r1 * 32 + dp]);
                acc.x += v0.x + v1.x;
                acc.y += v0.y + v1.y;
            }
            for (; e < deg; e += 2) {
                float2 v = bf16x2_unpack(xs[(size_t)seg[e] * 32 + dp]);
                acc.x += v.x;
                acc.y += v.y;
            }
            acc.x += __shfl_xor(acc.x, 32);
            acc.y += __shfl_xor(acc.y, 32);
            float2 sv = bf16x2_unpack(xs[(size_t)n * 32 + dp]);
            float dn = rsqrtf((float)(deg + 1));
            acc.x = (acc.x + sv.x) * dn;
            acc.y = (acc.y + sv.y) * dn;
        }
        if (sub == 0) hlu[(w * 16 + i) * 36 + dp] = bf16x2_pack(acc.x, acc.y);
    }
    __syncthreads();   // cheap; wave regions are private but keep ordering explicit

    // ---- phase B: 16x192 MFMA from LDS + fused epilogue ----
    int m = lane & 15, quad = lane >> 4;
    const short* hrow = hl + (w * 16 + m) * 72 + quad * 8;
    bf16x8 a0 = *(const bf16x8*)(hrow);
    bf16x8 a1 = *(const bf16x8*)(hrow + 32);

    f32x4 acc[12];
    #pragma unroll
    for (int t = 0; t < 12; t++) acc[t] = (f32x4)(0.0f);

    #pragma unroll
    for (int kh = 0; kh < 2; kh++) {
        bf16x8 a = kh ? a1 : a0;
        #pragma unroll
        for (int t = 0; t < 12; t++) {
            bf16x8 bf = *(const bf16x8*)(Bp + ((size_t)((kh * 12 + t) * 64 + lane)) * 8);
            acc[t] = __builtin_amdgcn_mfma_f32_16x16x32_bf16(a, bf, acc[t], 0, 0, 0);
        }
    }

    float wg[12];
    #pragma unroll
    for (int k = 0; k < 12; k++) wg[k] = Wg[k];       // [GATE_C=4][EXPERTS=3] row-major

    #pragma unroll
    for (int reg = 0; reg < 4; reg++) {
        int n = nbase + quad * 4 + reg;
        if (n >= NN) continue;
        float4 g = ((const float4*)gf)[n];
        float l0 = (g.x*wg[0] + g.y*wg[3] + g.z*wg[6] + g.w*wg[9])  * (1.0f/101.0f);
        float l1 = (g.x*wg[1] + g.y*wg[4] + g.z*wg[7] + g.w*wg[10]) * (1.0f/101.0f);
        float l2 = (g.x*wg[2] + g.y*wg[5] + g.z*wg[8] + g.w*wg[11]) * (1.0f/101.0f);
        float mx = fmaxf(l0, fmaxf(l1, l2));
        float e0 = __expf(l0 - mx), e1 = __expf(l1 - mx), e2 = __expf(l2 - mx);
        float inv = 1.0f / (e0 + e1 + e2);
        float g0 = e0 * inv, g1 = e1 * inv, g2 = e2 * inv;
        #pragma unroll
        for (int dpos = 0; dpos < 4; dpos++) {
            int d = dpos * 16 + m;
            float v0 = acc[0*4 + dpos][reg] + b[0*64 + d];
            float v1 = acc[1*4 + dpos][reg] + b[1*64 + d];
            float v2 = acc[2*4 + dpos][reg] + b[2*64 + d];
            float o = g0 * fmaxf(v0, 0.f) + g1 * fmaxf(v1, 0.f) + g2 * fmaxf(v2, 0.f);
            out[(size_t)n * 64 + d] = o;
        }
    }
}

extern "C" void kernel_launch(void* const* d_in, const int* in_sizes, int n_in,
                              void* d_out, int out_size, void* d_ws, size_t ws_size,
                              hipStream_t stream) {
    const float* x  = (const float*)d_in[0];
    const int*   ei = (const int*)d_in[1];
    const float* gf = (const float*)d_in[2];
    const float* W  = (const float*)d_in[3];
    const float* b  = (const float*)d_in[4];
    const float* Wg = (const float*)d_in[5];
    float* out = (float*)d_out;
    const int* rows = ei;        // edge_index[0] (sources)
    const int* cols = ei + NE;   // edge_index[1] (targets)

    char* ws = (char*)d_ws;
    size_t off = 0;
    auto alloc = [&](size_t bytes) {
        char* p = ws + off;
        off = (off + bytes + 255) & ~(size_t)255;
        return p;
    };
    int*            cur    = (int*)alloc(512 * 4);
    unsigned*       eb     = (unsigned*)alloc((size_t)NBUCK * CAPB * 4);
    int*            srcs2  = (int*)alloc((size_t)NBUCK * CAPB * 4);
    int2*           nsd    = (int2*)alloc((size_t)NN * 8);
    unsigned*       xs     = (unsigned*)alloc((size_t)NN * 32 * 4);
    __hip_bfloat16* Bp     = (__hip_bfloat16*)alloc(12288 * 2);

    hipMemsetAsync(cur, 0, 512 * 4, stream);

    bin_kernel<<<NCH, 256, 0, stream>>>(rows, cols, cur, eb);
    nodesort_kernel<<<NBUCK, 256, 0, stream>>>(cur, eb, x, srcs2, nsd, xs);
    wpack_kernel<<<48, 256, 0, stream>>>(W, Bp);
    fused_kernel<<<(NN + 63) / 64, 256, 0, stream>>>(srcs2, nsd, xs, (const short*)Bp,
                                                     b, gf, Wg, out);
}

// Round 11
// 195.638 us; speedup vs baseline: 1.2088x; 1.2088x over previous
//
#include <hip/hip_runtime.h>
#include <hip/hip_bf16.h>

#define NN 100000
#define NE 1600000
#define NT 6250      // NN/16 node-tiles for MFMA

#define NBUCK  511       // buckets of BRANGE destination nodes
#define BRANGE 196       // fits 8-bit local id
#define CAPB   3584      // bucket capacity: mean 3136, sigma 56 -> 8-sigma margin
#define CHUNK  4096      // edges per bin block (391 blocks -> ~6 waves/CU)
#define NCH    391       // ceil(NE/CHUNK)

typedef __attribute__((ext_vector_type(8))) short bf16x8;
typedef __attribute__((ext_vector_type(4))) float f32x4;

__device__ inline float2 bf16x2_unpack(unsigned v) {
    float2 r;
    r.x = __uint_as_float(v << 16);
    r.y = __uint_as_float(v & 0xffff0000u);
    return r;
}
__device__ inline unsigned bf16x2_pack(float a, float b) {
    __hip_bfloat162 h2(__float2bfloat16(a), __float2bfloat16(b));
    unsigned u;
    __builtin_memcpy(&u, &h2, 4);
    return u;
}

// ---- phase 1: block-local counting sort by bucket + bulk-reserved dense runs ----
__global__ __launch_bounds__(256) void bin_kernel(const int* __restrict__ rows,
                                                  const int* __restrict__ cols,
                                                  int* __restrict__ cur,
                                                  unsigned* __restrict__ eb) {
    __shared__ int hist[512];
    __shared__ int excl[512];
    __shared__ int lcur[512];
    __shared__ int gbase[512];
    __shared__ int s2[256];
    __shared__ unsigned staged[CHUNK];
    __shared__ unsigned short bktarr[CHUNK];
    int t = threadIdx.x;
    int base = blockIdx.x * CHUNK;
    int cnt = min(CHUNK, NE - base);

    hist[t] = 0; hist[t + 256] = 0;
    __syncthreads();
    #pragma unroll
    for (int k = 0; k < CHUNK / 256; k++) {
        int i = k * 256 + t;
        if (i < cnt) {
            int c = cols[base + i];
            atomicAdd(&hist[(unsigned)c / BRANGE], 1);
        }
    }
    __syncthreads();
    // exclusive scan of 512 entries via pair trick (256-thread Hillis-Steele)
    int a0 = hist[2 * t], a1 = hist[2 * t + 1];
    s2[t] = a0 + a1;
    __syncthreads();
    #pragma unroll
    for (int off = 1; off < 256; off <<= 1) {
        int v = (t >= off) ? s2[t - off] : 0;
        __syncthreads();
        s2[t] += v;
        __syncthreads();
    }
    int pe = (t > 0) ? s2[t - 1] : 0;
    excl[2 * t] = pe;      excl[2 * t + 1] = pe + a0;
    lcur[2 * t] = pe;      lcur[2 * t + 1] = pe + a0;
    gbase[2 * t]     = a0 ? atomicAdd(cur + 2 * t, a0) : 0;
    gbase[2 * t + 1] = a1 ? atomicAdd(cur + 2 * t + 1, a1) : 0;
    __syncthreads();
    // sort records into LDS
    #pragma unroll
    for (int k = 0; k < CHUNK / 256; k++) {
        int i = k * 256 + t;
        if (i < cnt) {
            int c = cols[base + i];
            int r = rows[base + i];
            int bkt = (unsigned)c / BRANGE;
            int lp = atomicAdd(&lcur[bkt], 1);
            staged[lp] = ((unsigned)(c - bkt * BRANGE) << 24) | (unsigned)r;
            bktarr[lp] = (unsigned short)bkt;
        }
    }
    __syncthreads();
    // flat coalesced copy-out: consecutive i in a run -> consecutive gpos
    #pragma unroll
    for (int k = 0; k < CHUNK / 256; k++) {
        int i = k * 256 + t;
        if (i < cnt) {
            int bkt = bktarr[i];
            int pos = gbase[bkt] + (i - excl[bkt]);
            if (pos < CAPB) eb[(size_t)bkt * CAPB + pos] = staged[i];
        }
    }
}

// ---- phase 2: sort bucket records by dst node; emit (start,deg) only ----
__global__ __launch_bounds__(256) void nodesort_kernel(const int* __restrict__ cur,
                                                       const unsigned* __restrict__ eb,
                                                       int* __restrict__ srcs2,
                                                       int2* __restrict__ nsd) {
    __shared__ int hist[256];
    __shared__ int sx[256];
    __shared__ int lcur[BRANGE];
    int b = blockIdx.x, t = threadIdx.x;
    hist[t] = 0;
    __syncthreads();
    int cnt = min(cur[b], CAPB);
    const unsigned* seg = eb + (size_t)b * CAPB;
    for (int e = t; e < cnt; e += 256) atomicAdd(&hist[seg[e] >> 24], 1);
    __syncthreads();
    int h = hist[t];
    sx[t] = h;
    __syncthreads();
    #pragma unroll
    for (int off = 1; off < 256; off <<= 1) {
        int v = (t >= off) ? sx[t - off] : 0;
        __syncthreads();
        sx[t] += v;
        __syncthreads();
    }
    int ex = (t > 0) ? sx[t - 1] : 0;
    if (t < BRANGE) {
        lcur[t] = ex;
        int n = b * BRANGE + t;
        if (n < NN) nsd[n] = make_int2(ex, h);
    }
    __syncthreads();
    for (int e = t; e < cnt; e += 256) {
        unsigned rec = seg[e];
        int p = atomicAdd(&lcur[rec >> 24], 1);
        srcs2[(size_t)b * CAPB + p] = rec & 0xFFFFFFu;
    }
}

// ---- xs = bf16(x * rsqrt(deg+1)) : standalone, high-TLP dense stream ----
__global__ __launch_bounds__(256) void xscale_kernel(const float* __restrict__ x,
                                                     const int2* __restrict__ nsd,
                                                     unsigned* __restrict__ xs) {
    int i = blockIdx.x * 256 + threadIdx.x;           // NN*32 threads exactly
    int n = i >> 5;
    int d = (i & 31) * 2;
    float2 v = *(const float2*)(x + (size_t)n * 64 + d);
    float dv = rsqrtf((float)(nsd[n].y + 1));
    xs[i] = bf16x2_pack(v.x * dv, v.y * dv);
}

// ---- phase 3: gather-aggregate, cascade-unrolled (up to 8 rows in flight/half) ----
__global__ __launch_bounds__(256) void gather_kernel(const int* __restrict__ srcs2,
                                                     const int2* __restrict__ nsd,
                                                     const unsigned* __restrict__ xs,
                                                     unsigned* __restrict__ hbu) {
    int wave = threadIdx.x >> 6;
    int n = blockIdx.x * 4 + wave;                    // grid 25000 exact
    int lane = threadIdx.x & 63;
    int sub = lane >> 5;
    int dp = lane & 31;

    int2 sd = nsd[n];
    int deg = sd.y;
    int bkt = (unsigned)n / BRANGE;
    const int* seg = srcs2 + (size_t)bkt * CAPB + sd.x;

    float2 acc = make_float2(0.f, 0.f);
    int e = sub;
    for (; e + 14 < deg; e += 16) {                   // 8 rows in flight per half
        int r0 = seg[e];      int r1 = seg[e + 2];
        int r2 = seg[e + 4];  int r3 = seg[e + 6];
        int r4 = seg[e + 8];  int r5 = seg[e + 10];
        int r6 = seg[e + 12]; int r7 = seg[e + 14];
        float2 v0 = bf16x2_unpack(xs[(size_t)r0 * 32 + dp]);
        float2 v1 = bf16x2_unpack(xs[(size_t)r1 * 32 + dp]);
        float2 v2 = bf16x2_unpack(xs[(size_t)r2 * 32 + dp]);
        float2 v3 = bf16x2_unpack(xs[(size_t)r3 * 32 + dp]);
        float2 v4 = bf16x2_unpack(xs[(size_t)r4 * 32 + dp]);
        float2 v5 = bf16x2_unpack(xs[(size_t)r5 * 32 + dp]);
        float2 v6 = bf16x2_unpack(xs[(size_t)r6 * 32 + dp]);
        float2 v7 = bf16x2_unpack(xs[(size_t)r7 * 32 + dp]);
        acc.x += ((v0.x + v1.x) + (v2.x + v3.x)) + ((v4.x + v5.x) + (v6.x + v7.x));
        acc.y += ((v0.y + v1.y) + (v2.y + v3.y)) + ((v4.y + v5.y) + (v6.y + v7.y));
    }
    for (; e + 6 < deg; e += 8) {                     // 4 rows in flight
        int r0 = seg[e];     int r1 = seg[e + 2];
        int r2 = seg[e + 4]; int r3 = seg[e + 6];
        float2 v0 = bf16x2_unpack(xs[(size_t)r0 * 32 + dp]);
        float2 v1 = bf16x2_unpack(xs[(size_t)r1 * 32 + dp]);
        float2 v2 = bf16x2_unpack(xs[(size_t)r2 * 32 + dp]);
        float2 v3 = bf16x2_unpack(xs[(size_t)r3 * 32 + dp]);
        acc.x += (v0.x + v1.x) + (v2.x + v3.x);
        acc.y += (v0.y + v1.y) + (v2.y + v3.y);
    }
    for (; e + 2 < deg; e += 4) {                     // 2 rows in flight
        int r0 = seg[e]; int r1 = seg[e + 2];
        float2 v0 = bf16x2_unpack(xs[(size_t)r0 * 32 + dp]);
        float2 v1 = bf16x2_unpack(xs[(size_t)r1 * 32 + dp]);
        acc.x += v0.x + v1.x;
        acc.y += v0.y + v1.y;
    }
    for (; e < deg; e += 2) {
        float2 v = bf16x2_unpack(xs[(size_t)seg[e] * 32 + dp]);
        acc.x += v.x;
        acc.y += v.y;
    }
    acc.x += __shfl_xor(acc.x, 32);
    acc.y += __shfl_xor(acc.y, 32);
    float2 sv = bf16x2_unpack(xs[(size_t)n * 32 + dp]);
    float dn = rsqrtf((float)(deg + 1));
    unsigned packed = bf16x2_pack((acc.x + sv.x) * dn, (acc.y + sv.y) * dn);
    if (sub == 0) hbu[(size_t)n * 32 + dp] = packed;
}

// ---- pack Wcat[64 x 192] (3 experts side by side) into B-fragment order, bf16 ----
__global__ void wpack_kernel(const float* __restrict__ W, __hip_bfloat16* __restrict__ Bp) {
    int idx = blockIdx.x * 256 + threadIdx.x;         // 12288 total
    if (idx >= 12288) return;
    int j    = idx & 7;
    int lane = (idx >> 3) & 63;
    int rest = idx >> 9;                              // half*12 + t
    int t    = rest % 12;
    int kh   = rest / 12;
    int k    = kh * 32 + (lane >> 4) * 8 + j;
    int col  = t * 16 + (lane & 15);
    int i    = col >> 6;
    int d    = col & 63;
    Bp[idx] = __float2bfloat16(W[(i * 64 + k) * 64 + d]);
}

// ---- dense: [16-node tile] x [192 outs], K=64 bf16 MFMA; fused bias+relu+gate mix ----
__global__ __launch_bounds__(256) void mfma_kernel(const __hip_bfloat16* __restrict__ hb,
                                                   const short* __restrict__ Bp,
                                                   const float* __restrict__ b,
                                                   const float* __restrict__ gf,
                                                   const float* __restrict__ Wg,
                                                   float* __restrict__ out) {
    int wave = threadIdx.x >> 6;
    int lane = threadIdx.x & 63;
    int tile = blockIdx.x * 4 + wave;
    if (tile >= NT) return;
    int n0 = tile * 16;
    int m = lane & 15, quad = lane >> 4;

    const short* hrow = (const short*)hb + ((size_t)(n0 + m)) * 64 + quad * 8;
    bf16x8 a0 = *(const bf16x8*)(hrow);
    bf16x8 a1 = *(const bf16x8*)(hrow + 32);

    f32x4 acc[12];
    #pragma unroll
    for (int t = 0; t < 12; t++) acc[t] = (f32x4)(0.0f);

    #pragma unroll
    for (int kh = 0; kh < 2; kh++) {
        bf16x8 a = kh ? a1 : a0;
        #pragma unroll
        for (int t = 0; t < 12; t++) {
            bf16x8 bf = *(const bf16x8*)(Bp + ((size_t)((kh * 12 + t) * 64 + lane)) * 8);
            acc[t] = __builtin_amdgcn_mfma_f32_16x16x32_bf16(a, bf, acc[t], 0, 0, 0);
        }
    }

    float wg[12];
    #pragma unroll
    for (int k = 0; k < 12; k++) wg[k] = Wg[k];       // [GATE_C=4][EXPERTS=3] row-major

    #pragma unroll
    for (int reg = 0; reg < 4; reg++) {
        int n = n0 + quad * 4 + reg;
        float4 g = ((const float4*)gf)[n];
        float l0 = (g.x*wg[0] + g.y*wg[3] + g.z*wg[6] + g.w*wg[9])  * (1.0f/101.0f);
        float l1 = (g.x*wg[1] + g.y*wg[4] + g.z*wg[7] + g.w*wg[10]) * (1.0f/101.0f);
        float l2 = (g.x*wg[2] + g.y*wg[5] + g.z*wg[8] + g.w*wg[11]) * (1.0f/101.0f);
        float mx = fmaxf(l0, fmaxf(l1, l2));
        float e0 = __expf(l0 - mx), e1 = __expf(l1 - mx), e2 = __expf(l2 - mx);
        float inv = 1.0f / (e0 + e1 + e2);
        float g0 = e0 * inv, g1 = e1 * inv, g2 = e2 * inv;
        #pragma unroll
        for (int dpos = 0; dpos < 4; dpos++) {
            int d = dpos * 16 + m;
            float v0 = acc[0*4 + dpos][reg] + b[0*64 + d];
            float v1 = acc[1*4 + dpos][reg] + b[1*64 + d];
            float v2 = acc[2*4 + dpos][reg] + b[2*64 + d];
            float o = g0 * fmaxf(v0, 0.f) + g1 * fmaxf(v1, 0.f) + g2 * fmaxf(v2, 0.f);
            out[(size_t)n * 64 + d] = o;
        }
    }
}

extern "C" void kernel_launch(void* const* d_in, const int* in_sizes, int n_in,
                              void* d_out, int out_size, void* d_ws, size_t ws_size,
                              hipStream_t stream) {
    const float* x  = (const float*)d_in[0];
    const int*   ei = (const int*)d_in[1];
    const float* gf = (const float*)d_in[2];
    const float* W  = (const float*)d_in[3];
    const float* b  = (const float*)d_in[4];
    const float* Wg = (const float*)d_in[5];
    float* out = (float*)d_out;
    const int* rows = ei;        // edge_index[0] (sources)
    const int* cols = ei + NE;   // edge_index[1] (targets)

    char* ws = (char*)d_ws;
    size_t off = 0;
    auto alloc = [&](size_t bytes) {
        char* p = ws + off;
        off = (off + bytes + 255) & ~(size_t)255;
        return p;
    };
    int*            cur    = (int*)alloc(512 * 4);
    unsigned*       eb     = (unsigned*)alloc((size_t)NBUCK * CAPB * 4);
    int*            srcs2  = (int*)alloc((size_t)NBUCK * CAPB * 4);
    int2*           nsd    = (int2*)alloc((size_t)NN * 8);
    unsigned*       xs     = (unsigned*)alloc((size_t)NN * 32 * 4);
    unsigned*       hbu    = (unsigned*)alloc((size_t)NN * 32 * 4);
    __hip_bfloat16* Bp     = (__hip_bfloat16*)alloc(12288 * 2);

    hipMemsetAsync(cur, 0, 512 * 4, stream);

    bin_kernel<<<NCH, 256, 0, stream>>>(rows, cols, cur, eb);
    nodesort_kernel<<<NBUCK, 256, 0, stream>>>(cur, eb, srcs2, nsd);
    xscale_kernel<<<NN * 32 / 256, 256, 0, stream>>>(x, nsd, xs);
    wpack_kernel<<<48, 256, 0, stream>>>(W, Bp);
    gather_kernel<<<NN / 4, 256, 0, stream>>>(srcs2, nsd, xs, hbu);
    mfma_kernel<<<(NT + 3) / 4, 256, 0, stream>>>((const __hip_bfloat16*)hbu,
                                                  (const short*)Bp, b, gf, Wg, out);
}